// Round 6
// baseline (141.476 us; speedup 1.0000x reference)
//
#include <hip/hip_runtime.h>
#include <math.h>

#define Bsz 64
#define Tn 200
#define NUMC 2000
#define DS 128
#define SM 50
#define NTOK (Bsz*Tn)
#define WVS2 5       // scan waves per block
#define MPW 10       // m per scan wave
#define CH 40        // t-chunk staged in LDS per double-buffer phase
#define NCH (Tn/CH)  // 5 chunks
#define SEP 44       // padded t-stride for se/sa rows (44: b64 reads ~4-way max)
#define WROW 60      // padded w row: 5 groups x 12 (16B-aligned group starts)

typedef __attribute__((ext_vector_type(8))) short bfrag;
typedef __attribute__((ext_vector_type(4))) float f32x4;
typedef __attribute__((ext_vector_type(2))) float f32x2;
typedef __attribute__((ext_vector_type(4))) unsigned int u32x4;

__device__ __forceinline__ unsigned short f2bf(float x) {
    unsigned int u = __builtin_bit_cast(unsigned int, x);
    u = u + 0x7fffu + ((u >> 16) & 1u);   // RNE
    return (unsigned short)(u >> 16);
}
__device__ __forceinline__ unsigned int pack2(float a, float b) {
    return (unsigned int)f2bf(a) | ((unsigned int)f2bf(b) << 16);
}
__device__ __forceinline__ bfrag mk_frag(f32x4 x, f32x4 y) {
    u32x4 t;
    t[0] = pack2(x[0], x[1]); t[1] = pack2(x[2], x[3]);
    t[2] = pack2(y[0], y[1]); t[3] = pack2(y[2], y[3]);
    return __builtin_bit_cast(bfrag, t);
}

// fast transcendentals: v_exp_f32 / v_rcp_f32 (~1e-6 rel err, invisible at bf16 grade)
__device__ __forceinline__ float fast_exp(float x)  { return __builtin_amdgcn_exp2f(x * 1.44269504f); }
__device__ __forceinline__ float fast_rcp(float x)  { return __builtin_amdgcn_rcpf(x); }
__device__ __forceinline__ float fast_sigmoid(float x) { return fast_rcp(1.f + fast_exp(-x)); }
__device__ __forceinline__ float fast_tanh(float x) { return 1.f - 2.f * fast_rcp(fast_exp(2.f * x) + 1.f); }

// ---------------- K0: cast weights into MFMA b-frag block layout ----------------
// lane L holds W[n = nt*16 + (L&15)][k = ki*32 + (L>>4)*8 + j], j=0..7.
// Bea: rows 0-127 = e_W, 128-255 = a_W          (16 n-tiles)
// Bkm: rows 0-127 = f_W[:,128:256], 128-177 = Mk, 178-191 = 0   (12 n-tiles)
// Bf0: rows 0-127 = f_W[:,0:128]                (8 n-tiles)
__global__ __launch_bounds__(256) void k0_cast(
    const float* __restrict__ eW, const float* __restrict__ aW,
    const float* __restrict__ fW, const float* __restrict__ Mk,
    unsigned int* __restrict__ BeaU, unsigned int* __restrict__ BkmU,
    unsigned int* __restrict__ Bf0U)
{
    const int g = blockIdx.x * 256 + threadIdx.x;
    if (g >= 9216) return;
    int gm, mat;
    unsigned int* dst;
    if (g < 4096)      { mat = 0; gm = g;        dst = BeaU; }
    else if (g < 7168) { mat = 1; gm = g - 4096; dst = BkmU; }
    else               { mat = 2; gm = g - 7168; dst = Bf0U; }
    const int nt = gm >> 8, r = gm & 255, ki = r >> 6, L = r & 63;
    const int n = nt * 16 + (L & 15);
    const int k = ki * 32 + (L >> 4) * 8;

    const float* src = nullptr;
    if (mat == 0) {
        src = (n < 128) ? (eW + (size_t)n * DS + k) : (aW + (size_t)(n - 128) * DS + k);
    } else if (mat == 1) {
        if (n < 128)      src = fW + (size_t)n * (2 * DS) + DS + k;
        else if (n < 128 + SM) src = Mk + (size_t)(n - 128) * DS + k;
    } else {
        src = fW + (size_t)n * (2 * DS) + k;
    }
    float v[8];
    #pragma unroll
    for (int j = 0; j < 8; j++) v[j] = src ? src[j] : 0.f;
    u32x4 o;
    o[0] = pack2(v[0], v[1]); o[1] = pack2(v[2], v[3]);
    o[2] = pack2(v[4], v[5]); o[3] = pack2(v[6], v[7]);
    ((u32x4*)dst)[gm] = o;
}

// ---------------- K1: 7 single-purpose waves per 16-token tile (5600 blocks) ----------------
// role 0/1: e cols 0-63/64-127 (V @ Bea[0:8],  sigmoid)
// role 2/3: a cols 0-63/64-127 (V @ Bea[8:16], tanh)
// role 4/5: kp cols 0-63/64-127 (K @ Bkm[0:8])
// role 6  : w logits (K @ Bkm[8:12]) + wave-parallel softmax
__global__ __launch_bounds__(64, 4) void k1_gemm(
    const int* __restrict__ skill, const int* __restrict__ answer,
    const float* __restrict__ k_emb, const float* __restrict__ v_emb,
    const unsigned int* __restrict__ BeaU, const unsigned int* __restrict__ BkmU,
    const float* __restrict__ eB, const float* __restrict__ aB,
    float* __restrict__ w_buf, float* __restrict__ e_buf,
    float* __restrict__ a_buf, float* __restrict__ kp_buf)
{
    const int bid = blockIdx.x;
    const int tile = bid / 7, role = bid % 7;
    const int L = threadIdx.x, L15 = L & 15, quad = L >> 4;
    const int tok0 = tile * 16;
    const int tokA = tok0 + L15;
    const int row0 = tok0 + quad * 4;

    const int s = skill[tokA];
    const float* ap;
    if (role < 4) {
        const int an = answer[tokA];
        const int ax = (an == 2) ? 1 : an;
        ap = v_emb + ((size_t)(s + NUMC * ax)) * DS + quad * 8;
    } else {
        ap = k_emb + (size_t)s * DS + quad * 8;
    }
    bfrag Af[4];
    #pragma unroll
    for (int ki = 0; ki < 4; ki++) {
        const f32x4* a4 = (const f32x4*)(ap + ki * 32);
        Af[ki] = mk_frag(a4[0], a4[1]);
    }

    const bfrag* Bp = (role < 4) ? (const bfrag*)BeaU : (const bfrag*)BkmU;
    const int g0 = (role < 4) ? role * 4 : (role - 4) * 4;

    f32x4 acc[4];
    #pragma unroll
    for (int t = 0; t < 4; t++) acc[t] = (f32x4){0.f,0.f,0.f,0.f};

    // B in two 2-tile halves to keep VGPRs under the (64,4) cap
    #pragma unroll
    for (int half = 0; half < 2; half++) {
        bfrag bh[2][4];
        #pragma unroll
        for (int tt = 0; tt < 2; tt++)
            #pragma unroll
            for (int ki = 0; ki < 4; ki++)
                bh[tt][ki] = Bp[(size_t)((g0 + half * 2 + tt) * 4 + ki) * 64 + L];
        #pragma unroll
        for (int ki = 0; ki < 4; ki++)
            #pragma unroll
            for (int tt = 0; tt < 2; tt++)
                acc[half * 2 + tt] = __builtin_amdgcn_mfma_f32_16x16x32_bf16(
                    Af[ki], bh[tt][ki], acc[half * 2 + tt], 0, 0, 0);
    }

    if (role == 6) {
        #pragma unroll
        for (int reg = 0; reg < 4; reg++) {
            float mx = -1e30f;
            #pragma unroll
            for (int t = 0; t < 4; t++) { const int c = t * 16 + L15; if (c < SM) mx = fmaxf(mx, acc[t][reg]); }
            #pragma unroll
            for (int msk = 1; msk <= 8; msk <<= 1) mx = fmaxf(mx, __shfl_xor(mx, msk));
            float ex[4]; float ssum = 0.f;
            #pragma unroll
            for (int t = 0; t < 4; t++) {
                const int c = t * 16 + L15;
                ex[t] = (c < SM) ? fast_exp(acc[t][reg] - mx) : 0.f;
                ssum += ex[t];
            }
            #pragma unroll
            for (int msk = 1; msk <= 8; msk <<= 1) ssum += __shfl_xor(ssum, msk);
            const float inv = fast_rcp(ssum);
            float* wp = w_buf + (size_t)(row0 + reg) * SM;
            #pragma unroll
            for (int t = 0; t < 4; t++) { const int c = t * 16 + L15; if (c < SM) wp[c] = ex[t] * inv; }
        }
    } else {
        const int nb = (role & 1) * 64;
        float* obuf = (role < 2) ? e_buf : (role < 4) ? a_buf : kp_buf;
        const float* bias = (role < 2) ? eB : aB;
        #pragma unroll
        for (int t = 0; t < 4; t++) {
            const int n = nb + t * 16 + L15;
            const float bv = (role < 4) ? bias[n] : 0.f;
            #pragma unroll
            for (int reg = 0; reg < 4; reg++) {
                float v = acc[t][reg] + bv;
                if (role < 2)      v = fast_sigmoid(v);
                else if (role < 4) v = fast_tanh(v);
                obuf[(size_t)(row0 + reg) * DS + n] = v;
            }
        }
    }
}

// ---------------- K2: scan; block = (b, d-half), 5 waves x 10 m; vectorized LDS ----------------
// Round-5 post-mortem: k2 was LDS-INSTRUCTION-issue bound (720 scalar b32 ops/tile ~ 3700
// cyc/tile = 38 us). Fixes: (1) 5 waves x 10 m halves e/a read duplication and partial
// count; (2) se/sa in [d][t] layout -> one ds_read_b64 per 2t; (3) w pre-grouped
// [t][5][12] -> wave-uniform broadcast b128+b128+b64 per t; (4) reduce vectorized f32x2,
// packed u32 global store. Chunked double-buffer staging + T14 issue-early kept from r5.
__global__ __launch_bounds__(320) void k2_scan(
    const float* __restrict__ w_buf, const float* __restrict__ e_buf,
    const float* __restrict__ a_buf, const float* __restrict__ Mv0,
    unsigned short* __restrict__ reads)
{
    const int bi   = blockIdx.x;          // 0..127
    const int b    = bi >> 1;
    const int dh   = bi & 1;
    const int tid  = threadIdx.x;
    const int wv   = tid >> 6;            // 0..4 = m-group (10 m each)
    const int L    = tid & 63;
    const int d    = dh * 64 + L;
    const int m0   = wv * MPW;
    const int base = b * Tn;

    __shared__ __align__(16) float se_s[2][64][SEP];        // 22.5 KB
    __shared__ __align__(16) float sa_s[2][64][SEP];        // 22.5 KB
    __shared__ __align__(16) float w_s[2][CH][WROW];        // 19.2 KB
    __shared__ __align__(16) float red[2][WVS2][8][64];     // 20.5 KB  (total ~85 KB)

    float Mv[MPW];
    #pragma unroll
    for (int m = 0; m < MPW; m++) Mv[m] = Mv0[(size_t)(m0 + m) * DS + d];

    const int srow = tid >> 6, scol = tid & 63;   // staging coords: 5 rows x 64 cols/pass

    // ---- prologue: stage chunk 0 into buffer 0 ----
    {
        #pragma unroll
        for (int pass = 0; pass < 8; pass++) {
            const int row = pass * 5 + srow;
            se_s[0][scol][row] = e_buf[(size_t)(base + row) * DS + dh * 64 + scol];
            sa_s[0][scol][row] = a_buf[(size_t)(base + row) * DS + dh * 64 + scol];
        }
        #pragma unroll
        for (int pass = 0; pass < 7; pass++) {
            const int j = tid + pass * 320;
            if (j < CH * SM) {
                const int t = j / SM, m = j % SM;
                w_s[0][t][(m / MPW) * 12 + (m % MPW)] = w_buf[(size_t)base * SM + j];
            }
        }
    }
    __syncthreads();

    // register ring: 2 slots of 2t (4t lookahead over ~120cyc LDS latency)
    f32x4 wlo[2][2], whi[2][2];
    f32x2 wtl[2][2], sev[2], sav[2];
    int p = 0;

    #define LOADR(SL, TL)                                                      \
        { const int tl_ = (TL);                                                \
          if (tl_ < CH) {                                                      \
            sev[SL] = *(const f32x2*)&se_s[p][L][tl_];                         \
            sav[SL] = *(const f32x2*)&sa_s[p][L][tl_];                         \
            _Pragma("unroll")                                                  \
            for (int q_ = 0; q_ < 2; q_++) {                                   \
                const float* wp_ = &w_s[p][tl_ + q_][wv * 12];                 \
                wlo[SL][q_] = *(const f32x4*)wp_;                              \
                whi[SL][q_] = *(const f32x4*)(wp_ + 4);                        \
                wtl[SL][q_] = *(const f32x2*)(wp_ + 8);                        \
            } } }

    LOADR(0, 0) LOADR(1, 2)

    for (int c = 0; c < NCH; c++) {
        // T14 issue-early: next chunk's coalesced global loads -> registers
        float st_e[8], st_a[8], st_w[7];
        if (c + 1 < NCH) {
            const int t0n = (c + 1) * CH;
            #pragma unroll
            for (int pass = 0; pass < 8; pass++) {
                const int row = pass * 5 + srow;
                st_e[pass] = e_buf[(size_t)(base + t0n + row) * DS + dh * 64 + scol];
                st_a[pass] = a_buf[(size_t)(base + t0n + row) * DS + dh * 64 + scol];
            }
            #pragma unroll
            for (int pass = 0; pass < 7; pass++) {
                const int j = tid + pass * 320;
                st_w[pass] = (j < CH * SM) ? w_buf[(size_t)(base + t0n) * SM + j] : 0.f;
            }
        }

        #pragma unroll 1
        for (int ti = 0; ti < 5; ti++) {
            const int tlb = ti * 8;
            const int pr  = (c * 5 + ti) & 1;
            #pragma unroll
            for (int s = 0; s < 4; s++) {
                const int slot = s & 1;
                #pragma unroll
                for (int q = 0; q < 2; q++) {
                    const float ev = sev[slot][q], av = sav[slot][q];
                    float rd = 0.f;
                    #pragma unroll
                    for (int m = 0; m < MPW; m++) {
                        const float wm = (m < 4) ? wlo[slot][q][m]
                                       : (m < 8) ? whi[slot][q][m - 4]
                                                 : wtl[slot][q][m - 8];
                        rd = fmaf(wm, Mv[m], rd);                            // read uses OLD Mv
                        Mv[m] = fmaf(-wm, fmaf(ev, Mv[m], -av), Mv[m]);      // Mv*(1-w*e)+w*a
                    }
                    red[pr][wv][s * 2 + q][L] = rd;
                }
                LOADR(slot, tlb + s * 2 + 4)
            }
            __syncthreads();
            // cross-wave reduce: 512 outputs as 256 x f32x2; conflict-free b64 reads;
            // packed bf16 u32 store. Safe w/o 2nd barrier: red[pr] is re-written 2 tiles
            // later, after the NEXT barrier.
            if (tid < 256) {
                const int tt = tid >> 5, dd2 = tid & 31;
                f32x2 s2 = *(const f32x2*)&red[pr][0][tt][dd2 * 2];
                #pragma unroll
                for (int g = 1; g < WVS2; g++)
                    s2 += *(const f32x2*)&red[pr][g][tt][dd2 * 2];
                *(unsigned int*)&reads[(size_t)(base + c * CH + tlb + tt) * DS + dh * 64 + dd2 * 2]
                    = pack2(s2[0], s2[1]);
            }
        }

        // write-late: commit next chunk into the other LDS buffer, barrier, re-prime ring
        if (c + 1 < NCH) {
            #pragma unroll
            for (int pass = 0; pass < 8; pass++) {
                const int row = pass * 5 + srow;
                se_s[p ^ 1][scol][row] = st_e[pass];
                sa_s[p ^ 1][scol][row] = st_a[pass];
            }
            #pragma unroll
            for (int pass = 0; pass < 7; pass++) {
                const int j = tid + pass * 320;
                if (j < CH * SM) {
                    const int t = j / SM, m = j % SM;
                    w_s[p ^ 1][t][(m / MPW) * 12 + (m % MPW)] = st_w[pass];
                }
            }
            __syncthreads();
            p ^= 1;
            LOADR(0, 0) LOADR(1, 2)
        }
    }
    #undef LOADR
}

// ---------------- K3: 2-wave blocks (n-halves); f-GEMM + pred with LDS combine ----------------
__global__ __launch_bounds__(128, 2) void k3_gemm(
    const unsigned short* __restrict__ reads, const float* __restrict__ kp_buf,
    const unsigned int* __restrict__ Bf0U, const float* __restrict__ fB,
    const float* __restrict__ pW, const float* __restrict__ pB,
    const int* __restrict__ skill, float* __restrict__ out)
{
    const int tid = threadIdx.x;
    const int wv  = tid >> 6;          // n-half: 0 -> cols 0-63, 1 -> cols 64-127
    const int L   = tid & 63, L15 = L & 15, quad = L >> 4;
    const int tok0 = blockIdx.x * 16;
    const int tokA = tok0 + L15;
    const int row0 = tok0 + quad * 4;

    __shared__ float sm[2][16];

    // A-frags: final reads, already bf16 in frag element order
    bfrag Rf[4];
    #pragma unroll
    for (int ki = 0; ki < 4; ki++)
        Rf[ki] = *(const bfrag*)(reads + (size_t)tokA * DS + ki * 32 + quad * 8);

    const bfrag* Bf0 = (const bfrag*)Bf0U;
    const int g0 = wv * 4;

    f32x4 acc[4];
    #pragma unroll
    for (int t = 0; t < 4; t++) acc[t] = (f32x4){0.f,0.f,0.f,0.f};

    #pragma unroll
    for (int half = 0; half < 2; half++) {
        bfrag bh[2][4];
        #pragma unroll
        for (int tt = 0; tt < 2; tt++)
            #pragma unroll
            for (int ki = 0; ki < 4; ki++)
                bh[tt][ki] = Bf0[(size_t)((g0 + half * 2 + tt) * 4 + ki) * 64 + L];
        #pragma unroll
        for (int ki = 0; ki < 4; ki++)
            #pragma unroll
            for (int tt = 0; tt < 2; tt++)
                acc[half * 2 + tt] = __builtin_amdgcn_mfma_f32_16x16x32_bf16(
                    Rf[ki], bh[tt][ki], acc[half * 2 + tt], 0, 0, 0);
    }

    const int nb = wv * 64;
    float f[4][4];   // [reg][t]
    #pragma unroll
    for (int t = 0; t < 4; t++) {
        const int n = nb + t * 16 + L15;
        const float fb = fB[n];
        #pragma unroll
        for (int reg = 0; reg < 4; reg++)
            f[reg][t] = fast_tanh(acc[t][reg] + kp_buf[(size_t)(row0 + reg) * DS + n] + fb);
    }

    // pred partial: this wave's 64-dim contribution, reduced over the 16 lanes (L15)
    #pragma unroll
    for (int reg = 0; reg < 4; reg++) {
        const int tok = row0 + reg;
        const int t = tok % Tn;
        const bool act = (t < Tn - 1);
        float contrib = 0.f;
        if (act) {
            const int sn = skill[tok + 1];
            const int ix = (sn < NUMC) ? sn : (NUMC - 1);
            const float* pr = pW + (size_t)ix * DS + nb + L15;
            #pragma unroll
            for (int t4 = 0; t4 < 4; t4++)
                contrib = fmaf(f[reg][t4], pr[t4 * 16], contrib);
        }
        #pragma unroll
        for (int msk = 1; msk <= 8; msk <<= 1)
            contrib += __shfl_xor(contrib, msk);
        if (L15 == 0) sm[wv][quad * 4 + reg] = contrib;
    }
    __syncthreads();
    if (tid < 16) {
        const int tok = tok0 + tid;
        const int t = tok % Tn;
        if (t < Tn - 1) {
            const int sn = skill[tok + 1];
            const int ix = (sn < NUMC) ? sn : (NUMC - 1);
            const float val = sm[0][tid] + sm[1][tid] + pB[ix];
            out[(size_t)(tok / Tn) * (Tn - 1) + t] = (sn < NUMC) ? fast_sigmoid(val) : 0.f;
        }
    }
}

extern "C" void kernel_launch(void* const* d_in, const int* in_sizes, int n_in,
                              void* d_out, int out_size, void* d_ws, size_t ws_size,
                              hipStream_t stream)
{
    const int*   skill  = (const int*)  d_in[0];
    const int*   answer = (const int*)  d_in[1];
    const float* k_emb  = (const float*)d_in[2];
    const float* v_emb  = (const float*)d_in[3];
    const float* Mk     = (const float*)d_in[4];
    const float* Mv0    = (const float*)d_in[5];
    const float* f_W    = (const float*)d_in[6];
    const float* f_b    = (const float*)d_in[7];
    const float* p_W    = (const float*)d_in[8];
    const float* p_b    = (const float*)d_in[9];
    const float* e_W    = (const float*)d_in[10];
    const float* e_b    = (const float*)d_in[11];
    const float* a_W    = (const float*)d_in[12];
    const float* a_b    = (const float*)d_in[13];
    float* out = (float*)d_out;

    float* ws     = (float*)d_ws;
    float* w_buf  = ws;                                   // NTOK*SM
    float* e_buf  = w_buf  + (size_t)NTOK*SM;             // NTOK*DS
    float* a_buf  = e_buf  + (size_t)NTOK*DS;             // NTOK*DS
    float* kp_buf = a_buf  + (size_t)NTOK*DS;             // NTOK*DS
    unsigned short* reads = (unsigned short*)(kp_buf + (size_t)NTOK*DS);  // NTOK*DS bf16
    unsigned int* BeaU = (unsigned int*)(reads + (size_t)NTOK*DS);
    unsigned int* BkmU = BeaU + 4096 * 4;
    unsigned int* Bf0U = BkmU + 3072 * 4;

    k0_cast<<<36, 256, 0, stream>>>(e_W, a_W, f_W, Mk, BeaU, BkmU, Bf0U);
    k1_gemm<<<7*(NTOK/16), 64, 0, stream>>>(skill, answer, k_emb, v_emb,
        BeaU, BkmU, e_b, a_b, w_buf, e_buf, a_buf, kp_buf);
    k2_scan<<<Bsz*2, 320, 0, stream>>>(w_buf, e_buf, a_buf, Mv0, reads);
    k3_gemm<<<NTOK/16, 128, 0, stream>>>(reads, kp_buf, Bf0U, f_b,
        p_W, p_b, skill, out);
}

// Round 7
// 138.762 us; speedup vs baseline: 1.0196x; 1.0196x over previous
//
#include <hip/hip_runtime.h>
#include <math.h>

#define Bsz 64
#define Tn 200
#define NUMC 2000
#define DS 128
#define SM 50
#define NTOK (Bsz*Tn)

typedef __attribute__((ext_vector_type(8))) short bfrag;
typedef __attribute__((ext_vector_type(4))) float f32x4;
typedef __attribute__((ext_vector_type(4))) unsigned int u32x4;

__device__ __forceinline__ unsigned short f2bf(float x) {
    unsigned int u = __builtin_bit_cast(unsigned int, x);
    u = u + 0x7fffu + ((u >> 16) & 1u);   // RNE
    return (unsigned short)(u >> 16);
}
__device__ __forceinline__ unsigned int pack2(float a, float b) {
    return (unsigned int)f2bf(a) | ((unsigned int)f2bf(b) << 16);
}
__device__ __forceinline__ bfrag mk_frag(f32x4 x, f32x4 y) {
    u32x4 t;
    t[0] = pack2(x[0], x[1]); t[1] = pack2(x[2], x[3]);
    t[2] = pack2(y[0], y[1]); t[3] = pack2(y[2], y[3]);
    return __builtin_bit_cast(bfrag, t);
}

// fast transcendentals: v_exp_f32 / v_rcp_f32 (~1e-6 rel err, invisible at bf16 grade)
__device__ __forceinline__ float fast_exp(float x)  { return __builtin_amdgcn_exp2f(x * 1.44269504f); }
__device__ __forceinline__ float fast_rcp(float x)  { return __builtin_amdgcn_rcpf(x); }
__device__ __forceinline__ float fast_sigmoid(float x) { return fast_rcp(1.f + fast_exp(-x)); }
__device__ __forceinline__ float fast_tanh(float x) { return 1.f - 2.f * fast_rcp(fast_exp(2.f * x) + 1.f); }

// ---------------- K0: cast weights into MFMA b-frag block layout ----------------
// lane L holds W[n = nt*16 + (L&15)][k = ki*32 + (L>>4)*8 + j], j=0..7.
// Bea: rows 0-127 = e_W, 128-255 = a_W          (16 n-tiles)
// Bkm: rows 0-127 = f_W[:,128:256], 128-177 = Mk, 178-191 = 0   (12 n-tiles)
// Bf0: rows 0-127 = f_W[:,0:128]                (8 n-tiles)
__global__ __launch_bounds__(256) void k0_cast(
    const float* __restrict__ eW, const float* __restrict__ aW,
    const float* __restrict__ fW, const float* __restrict__ Mk,
    unsigned int* __restrict__ BeaU, unsigned int* __restrict__ BkmU,
    unsigned int* __restrict__ Bf0U)
{
    const int g = blockIdx.x * 256 + threadIdx.x;
    if (g >= 9216) return;
    int gm, mat;
    unsigned int* dst;
    if (g < 4096)      { mat = 0; gm = g;        dst = BeaU; }
    else if (g < 7168) { mat = 1; gm = g - 4096; dst = BkmU; }
    else               { mat = 2; gm = g - 7168; dst = Bf0U; }
    const int nt = gm >> 8, r = gm & 255, ki = r >> 6, L = r & 63;
    const int n = nt * 16 + (L & 15);
    const int k = ki * 32 + (L >> 4) * 8;

    const float* src = nullptr;
    if (mat == 0) {
        src = (n < 128) ? (eW + (size_t)n * DS + k) : (aW + (size_t)(n - 128) * DS + k);
    } else if (mat == 1) {
        if (n < 128)      src = fW + (size_t)n * (2 * DS) + DS + k;
        else if (n < 128 + SM) src = Mk + (size_t)(n - 128) * DS + k;
    } else {
        src = fW + (size_t)n * (2 * DS) + k;
    }
    float v[8];
    #pragma unroll
    for (int j = 0; j < 8; j++) v[j] = src ? src[j] : 0.f;
    u32x4 o;
    o[0] = pack2(v[0], v[1]); o[1] = pack2(v[2], v[3]);
    o[2] = pack2(v[4], v[5]); o[3] = pack2(v[6], v[7]);
    ((u32x4*)dst)[gm] = o;
}

// ---------------- K1: 7 single-purpose waves per 16-token tile (5600 blocks) ----------------
// role 0/1: e cols 0-63/64-127 (V @ Bea[0:8],  sigmoid)
// role 2/3: a cols 0-63/64-127 (V @ Bea[8:16], tanh)
// role 4/5: kp cols 0-63/64-127 (K @ Bkm[0:8])
// role 6  : w logits (K @ Bkm[8:12]) + wave-parallel softmax -> padded w2 layout
//           w2[t][64]: m-groups {13,13,12,12} at col offsets {0,16,32,48}; pad cols = 0
__global__ __launch_bounds__(64, 4) void k1_gemm(
    const int* __restrict__ skill, const int* __restrict__ answer,
    const float* __restrict__ k_emb, const float* __restrict__ v_emb,
    const unsigned int* __restrict__ BeaU, const unsigned int* __restrict__ BkmU,
    const float* __restrict__ eB, const float* __restrict__ aB,
    float* __restrict__ w2, float* __restrict__ e_buf,
    float* __restrict__ a_buf, float* __restrict__ kp_buf)
{
    const int bid = blockIdx.x;
    const int tile = bid / 7, role = bid % 7;
    const int L = threadIdx.x, L15 = L & 15, quad = L >> 4;
    const int tok0 = tile * 16;
    const int tokA = tok0 + L15;
    const int row0 = tok0 + quad * 4;

    const int s = skill[tokA];
    const float* ap;
    if (role < 4) {
        const int an = answer[tokA];
        const int ax = (an == 2) ? 1 : an;
        ap = v_emb + ((size_t)(s + NUMC * ax)) * DS + quad * 8;
    } else {
        ap = k_emb + (size_t)s * DS + quad * 8;
    }
    bfrag Af[4];
    #pragma unroll
    for (int ki = 0; ki < 4; ki++) {
        const f32x4* a4 = (const f32x4*)(ap + ki * 32);
        Af[ki] = mk_frag(a4[0], a4[1]);
    }

    const bfrag* Bp = (role < 4) ? (const bfrag*)BeaU : (const bfrag*)BkmU;
    const int g0 = (role < 4) ? role * 4 : (role - 4) * 4;

    f32x4 acc[4];
    #pragma unroll
    for (int t = 0; t < 4; t++) acc[t] = (f32x4){0.f,0.f,0.f,0.f};

    // B in two 2-tile halves to keep VGPRs under the (64,4) cap
    #pragma unroll
    for (int half = 0; half < 2; half++) {
        bfrag bh[2][4];
        #pragma unroll
        for (int tt = 0; tt < 2; tt++)
            #pragma unroll
            for (int ki = 0; ki < 4; ki++)
                bh[tt][ki] = Bp[(size_t)((g0 + half * 2 + tt) * 4 + ki) * 64 + L];
        #pragma unroll
        for (int ki = 0; ki < 4; ki++)
            #pragma unroll
            for (int tt = 0; tt < 2; tt++)
                acc[half * 2 + tt] = __builtin_amdgcn_mfma_f32_16x16x32_bf16(
                    Af[ki], bh[tt][ki], acc[half * 2 + tt], 0, 0, 0);
    }

    if (role == 6) {
        #pragma unroll
        for (int reg = 0; reg < 4; reg++) {
            float mx = -1e30f;
            #pragma unroll
            for (int t = 0; t < 4; t++) { const int c = t * 16 + L15; if (c < SM) mx = fmaxf(mx, acc[t][reg]); }
            #pragma unroll
            for (int msk = 1; msk <= 8; msk <<= 1) mx = fmaxf(mx, __shfl_xor(mx, msk));
            float ex[4]; float ssum = 0.f;
            #pragma unroll
            for (int t = 0; t < 4; t++) {
                const int c = t * 16 + L15;
                ex[t] = (c < SM) ? fast_exp(acc[t][reg] - mx) : 0.f;
                ssum += ex[t];
            }
            #pragma unroll
            for (int msk = 1; msk <= 8; msk <<= 1) ssum += __shfl_xor(ssum, msk);
            const float inv = fast_rcp(ssum);
            float* wp = w2 + (size_t)(row0 + reg) * 64;
            // (t, L15) covers c = 0..63 exactly once; ex = 0 for c >= 50 -> pads zeroed
            #pragma unroll
            for (int t = 0; t < 4; t++) {
                const int c = t * 16 + L15;
                const int idx = (c < 13) ? c
                              : (c < 26) ? c + 3
                              : (c < 38) ? c + 6
                              : (c < 50) ? c + 10
                              : (c < 53) ? c - 37
                              : (c < 56) ? c - 24
                              : (c < 60) ? c - 12
                              : c;
                wp[idx] = ex[t] * inv;
            }
        }
    } else {
        const int nb = (role & 1) * 64;
        float* obuf = (role < 2) ? e_buf : (role < 4) ? a_buf : kp_buf;
        const float* bias = (role < 2) ? eB : aB;
        #pragma unroll
        for (int t = 0; t < 4; t++) {
            const int n = nb + t * 16 + L15;
            const float bv = (role < 4) ? bias[n] : 0.f;
            #pragma unroll
            for (int reg = 0; reg < 4; reg++) {
                float v = acc[t][reg] + bv;
                if (role < 2)      v = fast_sigmoid(v);
                else if (role < 4) v = fast_tanh(v);
                obuf[(size_t)(row0 + reg) * DS + n] = v;
            }
        }
    }
}

// ---------------- K2: scan; block = (b, d-half), 4 waves x 13 m ----------------
// r6 post-mortem: LDS pipe-bound with 8-way-conflicted b64s (stride-44 layout) + heavy
// broadcasts + 2+1+1+1 wave/SIMD VALU imbalance. Redesign:
//  - 4 waves (1/SIMD) x 13 m (zero-padded 16-col w groups -> guard-free inner loop)
//  - e/a: NO LDS; direct coalesced global b32 ring, 2 slots x 4t (8-t lookahead)
//  - w: per-tile LDS tile [2][8][64], coalesced 2-loads/thread, issue-early/write-late;
//       read as wave-uniform b128 broadcasts (conflict-free)
//  - red[2][4][64][12]: stride-12 b128 is perfectly bank-balanced (all 32 banks x 8)
//  - 1 barrier/tile; tid<128 reduce: 4x b128 + 4 contiguous u16 stores (bf16 reads)
__global__ __launch_bounds__(256) void k2_scan(
    const float* __restrict__ w2, const float* __restrict__ e_buf,
    const float* __restrict__ a_buf, const float* __restrict__ Mv0,
    unsigned short* __restrict__ reads)
{
    const int bi   = blockIdx.x;          // 0..127
    const int b    = bi >> 1;
    const int dh   = bi & 1;
    const int tid  = threadIdx.x;
    const int wv   = tid >> 6;            // 0..3 = m-group
    const int L    = tid & 63;
    const int d    = dh * 64 + L;
    const int base = b * Tn;
    const int gbase  = wv * 16;                                        // w2 col group
    const int mstart = (wv == 0) ? 0 : (wv == 1) ? 13 : (wv == 2) ? 26 : 38;

    __shared__ __align__(16) float red[2][4][64][12];   // 24.6 KB
    __shared__ __align__(16) float wt_s[2][8][64];      // 4 KB

    float Mv[13];
    #pragma unroll
    for (int j = 0; j < 13; j++) {
        const int m = mstart + j;
        Mv[j] = (m < SM) ? Mv0[(size_t)m * DS + d] : 0.f;   // overhang slots have w=0
    }

    // e/a register ring: 2 slots x 4t (8-t global-load lookahead)
    float re[2][4], ra[2][4];
    #define LOADEA(SL, T)                                                  \
        { const int t_ = (T);                                              \
          if (t_ < Tn) {                                                   \
            _Pragma("unroll")                                              \
            for (int i_ = 0; i_ < 4; i_++) {                               \
                re[SL][i_] = e_buf[(size_t)(base + t_ + i_) * DS + d];     \
                ra[SL][i_] = a_buf[(size_t)(base + t_ + i_) * DS + d];     \
            } } }

    const int r0 = tid >> 6, c0 = tid & 63;   // w staging coords (4 rows x 64 cols/pass)

    // prologue: stage w tile 0; prime e/a ring
    #pragma unroll
    for (int ps = 0; ps < 2; ps++)
        wt_s[0][ps * 4 + r0][c0] = w2[(size_t)(base + ps * 4 + r0) * 64 + c0];
    LOADEA(0, 0) LOADEA(1, 4)
    __syncthreads();

    int cur = 0;
    for (int ti = 0; ti < 25; ti++) {
        const int tb = ti * 8;
        const int pr = ti & 1;

        // issue-early: next tile's w rows -> regs (HBM/L2 latency hides under compute)
        float wst[2];
        if (ti < 24) {
            #pragma unroll
            for (int ps = 0; ps < 2; ps++)
                wst[ps] = w2[(size_t)(base + tb + 8 + ps * 4 + r0) * 64 + c0];
        }

        #pragma unroll
        for (int g = 0; g < 2; g++) {
            f32x4 rd;
            #pragma unroll
            for (int it = 0; it < 4; it++) {
                const int tl = g * 4 + it;
                const float* wp = &wt_s[cur][tl][gbase];          // wave-uniform
                const f32x4 wa = *(const f32x4*)wp;
                const f32x4 wb = *(const f32x4*)(wp + 4);
                const f32x4 wc = *(const f32x4*)(wp + 8);
                const float wd = wp[12];
                const float ev = re[g][it], av = ra[g][it];
                float r = 0.f;
                #pragma unroll
                for (int j = 0; j < 13; j++) {
                    const float wm = (j < 4) ? wa[j] : (j < 8) ? wb[j - 4]
                                   : (j < 12) ? wc[j - 8] : wd;
                    r = fmaf(wm, Mv[j], r);                          // read uses OLD Mv
                    Mv[j] = fmaf(-wm, fmaf(ev, Mv[j], -av), Mv[j]);  // Mv*(1-w*e)+w*a
                }
                rd[it] = r;
            }
            *(f32x4*)&red[pr][wv][L][g * 4] = rd;    // stride-12 b128: bank-balanced
            LOADEA(g, tb + g * 4 + 8)                // refill slot for next tile
        }

        // write-late: commit next w tile into the other buffer
        if (ti < 24) {
            #pragma unroll
            for (int ps = 0; ps < 2; ps++)
                wt_s[cur ^ 1][ps * 4 + r0][c0] = wst[ps];
        }
        __syncthreads();

        // cross-wave reduce: 128 threads x (one d, 4 t). Safe w/o 2nd barrier: red[pr]
        // is re-written 2 tiles later, after the NEXT barrier.
        if (tid < 128) {
            const int th = tid >> 6;        // t-half within tile
            const int dd = tid & 63;
            f32x4 s = *(const f32x4*)&red[pr][0][dd][th * 4];
            #pragma unroll
            for (int g2 = 1; g2 < 4; g2++)
                s += *(const f32x4*)&red[pr][g2][dd][th * 4];
            #pragma unroll
            for (int i = 0; i < 4; i++)
                reads[(size_t)(base + tb + th * 4 + i) * DS + dh * 64 + dd] = f2bf(s[i]);
        }
        cur ^= 1;
    }
    #undef LOADEA
}

// ---------------- K3: 2-wave blocks (n-halves); f-GEMM + pred with LDS combine ----------------
__global__ __launch_bounds__(128, 2) void k3_gemm(
    const unsigned short* __restrict__ reads, const float* __restrict__ kp_buf,
    const unsigned int* __restrict__ Bf0U, const float* __restrict__ fB,
    const float* __restrict__ pW, const float* __restrict__ pB,
    const int* __restrict__ skill, float* __restrict__ out)
{
    const int tid = threadIdx.x;
    const int wv  = tid >> 6;          // n-half: 0 -> cols 0-63, 1 -> cols 64-127
    const int L   = tid & 63, L15 = L & 15, quad = L >> 4;
    const int tok0 = blockIdx.x * 16;
    const int tokA = tok0 + L15;
    const int row0 = tok0 + quad * 4;

    __shared__ float sm[2][16];

    // A-frags: final reads, already bf16 in frag element order
    bfrag Rf[4];
    #pragma unroll
    for (int ki = 0; ki < 4; ki++)
        Rf[ki] = *(const bfrag*)(reads + (size_t)tokA * DS + ki * 32 + quad * 8);

    const bfrag* Bf0 = (const bfrag*)Bf0U;
    const int g0 = wv * 4;

    f32x4 acc[4];
    #pragma unroll
    for (int t = 0; t < 4; t++) acc[t] = (f32x4){0.f,0.f,0.f,0.f};

    #pragma unroll
    for (int half = 0; half < 2; half++) {
        bfrag bh[2][4];
        #pragma unroll
        for (int tt = 0; tt < 2; tt++)
            #pragma unroll
            for (int ki = 0; ki < 4; ki++)
                bh[tt][ki] = Bf0[(size_t)((g0 + half * 2 + tt) * 4 + ki) * 64 + L];
        #pragma unroll
        for (int ki = 0; ki < 4; ki++)
            #pragma unroll
            for (int tt = 0; tt < 2; tt++)
                acc[half * 2 + tt] = __builtin_amdgcn_mfma_f32_16x16x32_bf16(
                    Rf[ki], bh[tt][ki], acc[half * 2 + tt], 0, 0, 0);
    }

    const int nb = wv * 64;
    float f[4][4];   // [reg][t]
    #pragma unroll
    for (int t = 0; t < 4; t++) {
        const int n = nb + t * 16 + L15;
        const float fb = fB[n];
        #pragma unroll
        for (int reg = 0; reg < 4; reg++)
            f[reg][t] = fast_tanh(acc[t][reg] + kp_buf[(size_t)(row0 + reg) * DS + n] + fb);
    }

    // pred partial: this wave's 64-dim contribution, reduced over the 16 lanes (L15)
    #pragma unroll
    for (int reg = 0; reg < 4; reg++) {
        const int tok = row0 + reg;
        const int t = tok % Tn;
        const bool act = (t < Tn - 1);
        float contrib = 0.f;
        if (act) {
            const int sn = skill[tok + 1];
            const int ix = (sn < NUMC) ? sn : (NUMC - 1);
            const float* pr = pW + (size_t)ix * DS + nb + L15;
            #pragma unroll
            for (int t4 = 0; t4 < 4; t4++)
                contrib = fmaf(f[reg][t4], pr[t4 * 16], contrib);
        }
        #pragma unroll
        for (int msk = 1; msk <= 8; msk <<= 1)
            contrib += __shfl_xor(contrib, msk);
        if (L15 == 0) sm[wv][quad * 4 + reg] = contrib;
    }
    __syncthreads();
    if (tid < 16) {
        const int tok = tok0 + tid;
        const int t = tok % Tn;
        if (t < Tn - 1) {
            const int sn = skill[tok + 1];
            const int ix = (sn < NUMC) ? sn : (NUMC - 1);
            const float val = sm[0][tid] + sm[1][tid] + pB[ix];
            out[(size_t)(tok / Tn) * (Tn - 1) + t] = (sn < NUMC) ? fast_sigmoid(val) : 0.f;
        }
    }
}

extern "C" void kernel_launch(void* const* d_in, const int* in_sizes, int n_in,
                              void* d_out, int out_size, void* d_ws, size_t ws_size,
                              hipStream_t stream)
{
    const int*   skill  = (const int*)  d_in[0];
    const int*   answer = (const int*)  d_in[1];
    const float* k_emb  = (const float*)d_in[2];
    const float* v_emb  = (const float*)d_in[3];
    const float* Mk     = (const float*)d_in[4];
    const float* Mv0    = (const float*)d_in[5];
    const float* f_W    = (const float*)d_in[6];
    const float* f_b    = (const float*)d_in[7];
    const float* p_W    = (const float*)d_in[8];
    const float* p_b    = (const float*)d_in[9];
    const float* e_W    = (const float*)d_in[10];
    const float* e_b    = (const float*)d_in[11];
    const float* a_W    = (const float*)d_in[12];
    const float* a_b    = (const float*)d_in[13];
    float* out = (float*)d_out;

    float* ws     = (float*)d_ws;
    float* w2     = ws;                                   // NTOK*64 (padded w layout)
    float* e_buf  = w2     + (size_t)NTOK*64;             // NTOK*DS
    float* a_buf  = e_buf  + (size_t)NTOK*DS;             // NTOK*DS
    float* kp_buf = a_buf  + (size_t)NTOK*DS;             // NTOK*DS
    unsigned short* reads = (unsigned short*)(kp_buf + (size_t)NTOK*DS);  // NTOK*DS bf16
    unsigned int* BeaU = (unsigned int*)(reads + (size_t)NTOK*DS);
    unsigned int* BkmU = BeaU + 4096 * 4;
    unsigned int* Bf0U = BkmU + 3072 * 4;

    k0_cast<<<36, 256, 0, stream>>>(e_W, a_W, f_W, Mk, BeaU, BkmU, Bf0U);
    k1_gemm<<<7*(NTOK/16), 64, 0, stream>>>(skill, answer, k_emb, v_emb,
        BeaU, BkmU, e_b, a_b, w2, e_buf, a_buf, kp_buf);
    k2_scan<<<Bsz*2, 256, 0, stream>>>(w2, e_buf, a_buf, Mv0, reads);
    k3_gemm<<<NTOK/16, 128, 0, stream>>>(reads, kp_buf, Bf0U, f_b,
        p_W, p_b, skill, out);
}

// Round 8
// 137.454 us; speedup vs baseline: 1.0293x; 1.0095x over previous
//
#include <hip/hip_runtime.h>
#include <math.h>

#define Bsz 64
#define Tn 200
#define NUMC 2000
#define DS 128
#define SM 50
#define NTOK (Bsz*Tn)

typedef __attribute__((ext_vector_type(8))) short bfrag;
typedef __attribute__((ext_vector_type(4))) float f32x4;
typedef __attribute__((ext_vector_type(4))) unsigned int u32x4;

__device__ __forceinline__ unsigned short f2bf(float x) {
    unsigned int u = __builtin_bit_cast(unsigned int, x);
    u = u + 0x7fffu + ((u >> 16) & 1u);   // RNE
    return (unsigned short)(u >> 16);
}
__device__ __forceinline__ unsigned int pack2(float a, float b) {
    return (unsigned int)f2bf(a) | ((unsigned int)f2bf(b) << 16);
}
__device__ __forceinline__ bfrag mk_frag(f32x4 x, f32x4 y) {
    u32x4 t;
    t[0] = pack2(x[0], x[1]); t[1] = pack2(x[2], x[3]);
    t[2] = pack2(y[0], y[1]); t[3] = pack2(y[2], y[3]);
    return __builtin_bit_cast(bfrag, t);
}

// fast transcendentals: v_exp_f32 / v_rcp_f32 (~1e-6 rel err, invisible at bf16 grade)
__device__ __forceinline__ float fast_exp(float x)  { return __builtin_amdgcn_exp2f(x * 1.44269504f); }
__device__ __forceinline__ float fast_rcp(float x)  { return __builtin_amdgcn_rcpf(x); }
__device__ __forceinline__ float fast_sigmoid(float x) { return fast_rcp(1.f + fast_exp(-x)); }
__device__ __forceinline__ float fast_tanh(float x) { return 1.f - 2.f * fast_rcp(fast_exp(2.f * x) + 1.f); }

// ---------------- K0: cast weights into MFMA b-frag block layout ----------------
// lane L holds W[n = nt*16 + (L&15)][k = ki*32 + (L>>4)*8 + j], j=0..7.
// Bea: rows 0-127 = e_W, 128-255 = a_W          (16 n-tiles)
// Bkm: rows 0-127 = f_W[:,128:256], 128-177 = Mk, 178-191 = 0   (12 n-tiles)
// Bf0: rows 0-127 = f_W[:,0:128]                (8 n-tiles)
__global__ __launch_bounds__(256) void k0_cast(
    const float* __restrict__ eW, const float* __restrict__ aW,
    const float* __restrict__ fW, const float* __restrict__ Mk,
    unsigned int* __restrict__ BeaU, unsigned int* __restrict__ BkmU,
    unsigned int* __restrict__ Bf0U)
{
    const int g = blockIdx.x * 256 + threadIdx.x;
    if (g >= 9216) return;
    int gm, mat;
    unsigned int* dst;
    if (g < 4096)      { mat = 0; gm = g;        dst = BeaU; }
    else if (g < 7168) { mat = 1; gm = g - 4096; dst = BkmU; }
    else               { mat = 2; gm = g - 7168; dst = Bf0U; }
    const int nt = gm >> 8, r = gm & 255, ki = r >> 6, L = r & 63;
    const int n = nt * 16 + (L & 15);
    const int k = ki * 32 + (L >> 4) * 8;

    const float* src = nullptr;
    if (mat == 0) {
        src = (n < 128) ? (eW + (size_t)n * DS + k) : (aW + (size_t)(n - 128) * DS + k);
    } else if (mat == 1) {
        if (n < 128)      src = fW + (size_t)n * (2 * DS) + DS + k;
        else if (n < 128 + SM) src = Mk + (size_t)(n - 128) * DS + k;
    } else {
        src = fW + (size_t)n * (2 * DS) + k;
    }
    float v[8];
    #pragma unroll
    for (int j = 0; j < 8; j++) v[j] = src ? src[j] : 0.f;
    u32x4 o;
    o[0] = pack2(v[0], v[1]); o[1] = pack2(v[2], v[3]);
    o[2] = pack2(v[4], v[5]); o[3] = pack2(v[6], v[7]);
    ((u32x4*)dst)[gm] = o;
}

// ---------------- K1: 7 single-purpose waves per 16-token tile (5600 blocks) ----------------
// role 0/1: e cols 0-63/64-127 (V @ Bea[0:8],  sigmoid)
// role 2/3: a cols 0-63/64-127 (V @ Bea[8:16], tanh)
// role 4/5: kp cols 0-63/64-127 (K @ Bkm[0:8])
// role 6  : w logits (K @ Bkm[8:12]) + wave-parallel softmax -> padded w2 layout
//           w2[t][64]: m-groups {13,13,13,11} at col offsets {0,16,32,48}; pad cols = 0
__global__ __launch_bounds__(64, 4) void k1_gemm(
    const int* __restrict__ skill, const int* __restrict__ answer,
    const float* __restrict__ k_emb, const float* __restrict__ v_emb,
    const unsigned int* __restrict__ BeaU, const unsigned int* __restrict__ BkmU,
    const float* __restrict__ eB, const float* __restrict__ aB,
    float* __restrict__ w2, float* __restrict__ e_buf,
    float* __restrict__ a_buf, float* __restrict__ kp_buf)
{
    const int bid = blockIdx.x;
    const int tile = bid / 7, role = bid % 7;
    const int L = threadIdx.x, L15 = L & 15, quad = L >> 4;
    const int tok0 = tile * 16;
    const int tokA = tok0 + L15;
    const int row0 = tok0 + quad * 4;

    const int s = skill[tokA];
    const float* ap;
    if (role < 4) {
        const int an = answer[tokA];
        const int ax = (an == 2) ? 1 : an;
        ap = v_emb + ((size_t)(s + NUMC * ax)) * DS + quad * 8;
    } else {
        ap = k_emb + (size_t)s * DS + quad * 8;
    }
    bfrag Af[4];
    #pragma unroll
    for (int ki = 0; ki < 4; ki++) {
        const f32x4* a4 = (const f32x4*)(ap + ki * 32);
        Af[ki] = mk_frag(a4[0], a4[1]);
    }

    const bfrag* Bp = (role < 4) ? (const bfrag*)BeaU : (const bfrag*)BkmU;
    const int g0 = (role < 4) ? role * 4 : (role - 4) * 4;

    f32x4 acc[4];
    #pragma unroll
    for (int t = 0; t < 4; t++) acc[t] = (f32x4){0.f,0.f,0.f,0.f};

    // B in two 2-tile halves to keep VGPRs under the (64,4) cap
    #pragma unroll
    for (int half = 0; half < 2; half++) {
        bfrag bh[2][4];
        #pragma unroll
        for (int tt = 0; tt < 2; tt++)
            #pragma unroll
            for (int ki = 0; ki < 4; ki++)
                bh[tt][ki] = Bp[(size_t)((g0 + half * 2 + tt) * 4 + ki) * 64 + L];
        #pragma unroll
        for (int ki = 0; ki < 4; ki++)
            #pragma unroll
            for (int tt = 0; tt < 2; tt++)
                acc[half * 2 + tt] = __builtin_amdgcn_mfma_f32_16x16x32_bf16(
                    Af[ki], bh[tt][ki], acc[half * 2 + tt], 0, 0, 0);
    }

    if (role == 6) {
        #pragma unroll
        for (int reg = 0; reg < 4; reg++) {
            float mx = -1e30f;
            #pragma unroll
            for (int t = 0; t < 4; t++) { const int c = t * 16 + L15; if (c < SM) mx = fmaxf(mx, acc[t][reg]); }
            #pragma unroll
            for (int msk = 1; msk <= 8; msk <<= 1) mx = fmaxf(mx, __shfl_xor(mx, msk));
            float ex[4]; float ssum = 0.f;
            #pragma unroll
            for (int t = 0; t < 4; t++) {
                const int c = t * 16 + L15;
                ex[t] = (c < SM) ? fast_exp(acc[t][reg] - mx) : 0.f;
                ssum += ex[t];
            }
            #pragma unroll
            for (int msk = 1; msk <= 8; msk <<= 1) ssum += __shfl_xor(ssum, msk);
            const float inv = fast_rcp(ssum);
            float* wp = w2 + (size_t)(row0 + reg) * 64;
            // bijection c(0..63) -> col: real m c<50 packed 13/13/13/11 at group
            // offsets 0/16/32/48; c>=50 (ex=0) fills every pad col with zero.
            #pragma unroll
            for (int t = 0; t < 4; t++) {
                const int c = t * 16 + L15;
                const int idx = (c < 13) ? c
                              : (c < 26) ? c + 3
                              : (c < 39) ? c + 6
                              : (c < 50) ? c + 9
                              : (c < 53) ? c - 37
                              : (c < 56) ? c - 24
                              : (c < 59) ? c - 11
                              : c;
                wp[idx] = ex[t] * inv;
            }
        }
    } else {
        const int nb = (role & 1) * 64;
        float* obuf = (role < 2) ? e_buf : (role < 4) ? a_buf : kp_buf;
        const float* bias = (role < 2) ? eB : aB;
        #pragma unroll
        for (int t = 0; t < 4; t++) {
            const int n = nb + t * 16 + L15;
            const float bv = (role < 4) ? bias[n] : 0.f;
            #pragma unroll
            for (int reg = 0; reg < 4; reg++) {
                float v = acc[t][reg] + bv;
                if (role < 2)      v = fast_sigmoid(v);
                else if (role < 4) v = fast_tanh(v);
                obuf[(size_t)(row0 + reg) * DS + n] = v;
            }
        }
    }
}

// ---------------- K2: barrier-free scan; 512 one-wave blocks ----------------
// r5/r6/r7 post-mortem: three different k2s all ~equal -> the invariant was the
// per-tile __syncthreads, whose compiler-emitted s_waitcnt vmcnt(0) serially drains
// every in-flight load/store 25x per block (cross-XCD L3 ~600cyc each). Fix: put the
// m-split in LANES, not waves. 64 lanes = 4 m-groups (13/13/13/11, zero-padded w) x
// 16 d. m-reduction = 2x shfl_xor (masks 16,32) -- NO barrier, NO LDS, no drains.
// Grid = 64 b x 8 d-segments = 512 blocks (2/CU, all 256 CUs). Loads ride a 2-slot
// x 4-t register ring (8-t ~900cyc lookahead, never drained). Store: after the
// butterfly every lane holds the sum; lane's mg picks which of 4 buffered t it
// stores -> one global_store_short per lane per 4 t.
__global__ __launch_bounds__(64) void k2_scan(
    const float* __restrict__ w2, const float* __restrict__ e_buf,
    const float* __restrict__ a_buf, const float* __restrict__ Mv0,
    unsigned short* __restrict__ reads)
{
    const int bid  = blockIdx.x;            // 0..511
    const int b    = bid >> 3;
    const int dseg = bid & 7;
    const int lane = threadIdx.x;
    const int mg   = lane >> 4;             // 0..3 m-group
    const int dd   = lane & 15;
    const int d    = dseg * 16 + dd;
    const int mstart = mg * 13;             // groups 13/13/13/11 (+2 inert pads)
    const int gcol = mg * 16;               // w2 column group
    const int base = b * Tn;

    float Mv[13];
    #pragma unroll
    for (int j = 0; j < 13; j++) {
        const int m = (mstart + j < SM) ? (mstart + j) : (SM - 1);  // pad: finite value, w=0 forever
        Mv[j] = Mv0[(size_t)m * DS + d];
    }

    // 2-slot x 4-t register ring
    float ev[2][4], av[2][4], wd[2][4];
    f32x4 wa[2][4], wb[2][4], wc[2][4];

    #define LOADS(S, T0)                                                       \
        { _Pragma("unroll")                                                    \
          for (int i_ = 0; i_ < 4; i_++) {                                     \
              const int t_ = (T0) + i_;                                        \
              const int tc_ = (t_ < Tn) ? t_ : 0;                              \
              ev[S][i_] = e_buf[(size_t)(base + tc_) * DS + d];                \
              av[S][i_] = a_buf[(size_t)(base + tc_) * DS + d];                \
              const float* wp_ = w2 + (size_t)(base + tc_) * 64 + gcol;        \
              wa[S][i_] = *(const f32x4*)wp_;                                  \
              wb[S][i_] = *(const f32x4*)(wp_ + 4);                            \
              wc[S][i_] = *(const f32x4*)(wp_ + 8);                            \
              wd[S][i_] = wp_[12];                                             \
          } }

    #define PROC4(S, T0)                                                       \
        { float r4[4];                                                         \
          _Pragma("unroll")                                                    \
          for (int it = 0; it < 4; it++) {                                     \
              const float ev_ = ev[S][it], av_ = av[S][it];                    \
              float rd = 0.f;                                                  \
              _Pragma("unroll")                                                \
              for (int j = 0; j < 13; j++) {                                   \
                  const float wm = (j < 4) ? wa[S][it][j]                      \
                                 : (j < 8) ? wb[S][it][j - 4]                  \
                                 : (j < 12) ? wc[S][it][j - 8]                 \
                                 : wd[S][it];                                  \
                  rd = fmaf(wm, Mv[j], rd);                        /* old Mv */\
                  Mv[j] = fmaf(-wm, fmaf(ev_, Mv[j], -av_), Mv[j]);            \
              }                                                                \
              rd += __shfl_xor(rd, 16);                                        \
              rd += __shfl_xor(rd, 32);                                        \
              r4[it] = rd;                                                     \
          }                                                                    \
          const float val = (mg == 0) ? r4[0] : (mg == 1) ? r4[1]              \
                          : (mg == 2) ? r4[2] : r4[3];                         \
          reads[(size_t)(base + (T0) + mg) * DS + d] = f2bf(val); }

    LOADS(0, 0) LOADS(1, 4)

    for (int blk = 0; blk < 25; blk++) {
        const int t0 = blk * 8;
        PROC4(0, t0)     LOADS(0, t0 + 8)
        PROC4(1, t0 + 4) LOADS(1, t0 + 12)
    }
    #undef LOADS
    #undef PROC4
}

// ---------------- K3: 2-wave blocks (n-halves); f-GEMM + pred with LDS combine ----------------
__global__ __launch_bounds__(128, 2) void k3_gemm(
    const unsigned short* __restrict__ reads, const float* __restrict__ kp_buf,
    const unsigned int* __restrict__ Bf0U, const float* __restrict__ fB,
    const float* __restrict__ pW, const float* __restrict__ pB,
    const int* __restrict__ skill, float* __restrict__ out)
{
    const int tid = threadIdx.x;
    const int wv  = tid >> 6;          // n-half: 0 -> cols 0-63, 1 -> cols 64-127
    const int L   = tid & 63, L15 = L & 15, quad = L >> 4;
    const int tok0 = blockIdx.x * 16;
    const int tokA = tok0 + L15;
    const int row0 = tok0 + quad * 4;

    __shared__ float sm[2][16];

    // A-frags: final reads, already bf16 in frag element order
    bfrag Rf[4];
    #pragma unroll
    for (int ki = 0; ki < 4; ki++)
        Rf[ki] = *(const bfrag*)(reads + (size_t)tokA * DS + ki * 32 + quad * 8);

    const bfrag* Bf0 = (const bfrag*)Bf0U;
    const int g0 = wv * 4;

    f32x4 acc[4];
    #pragma unroll
    for (int t = 0; t < 4; t++) acc[t] = (f32x4){0.f,0.f,0.f,0.f};

    #pragma unroll
    for (int half = 0; half < 2; half++) {
        bfrag bh[2][4];
        #pragma unroll
        for (int tt = 0; tt < 2; tt++)
            #pragma unroll
            for (int ki = 0; ki < 4; ki++)
                bh[tt][ki] = Bf0[(size_t)((g0 + half * 2 + tt) * 4 + ki) * 64 + L];
        #pragma unroll
        for (int ki = 0; ki < 4; ki++)
            #pragma unroll
            for (int tt = 0; tt < 2; tt++)
                acc[half * 2 + tt] = __builtin_amdgcn_mfma_f32_16x16x32_bf16(
                    Rf[ki], bh[tt][ki], acc[half * 2 + tt], 0, 0, 0);
    }

    const int nb = wv * 64;
    float f[4][4];   // [reg][t]
    #pragma unroll
    for (int t = 0; t < 4; t++) {
        const int n = nb + t * 16 + L15;
        const float fb = fB[n];
        #pragma unroll
        for (int reg = 0; reg < 4; reg++)
            f[reg][t] = fast_tanh(acc[t][reg] + kp_buf[(size_t)(row0 + reg) * DS + n] + fb);
    }

    // pred partial: this wave's 64-dim contribution, reduced over the 16 lanes (L15)
    #pragma unroll
    for (int reg = 0; reg < 4; reg++) {
        const int tok = row0 + reg;
        const int t = tok % Tn;
        const bool act = (t < Tn - 1);
        float contrib = 0.f;
        if (act) {
            const int sn = skill[tok + 1];
            const int ix = (sn < NUMC) ? sn : (NUMC - 1);
            const float* pr = pW + (size_t)ix * DS + nb + L15;
            #pragma unroll
            for (int t4 = 0; t4 < 4; t4++)
                contrib = fmaf(f[reg][t4], pr[t4 * 16], contrib);
        }
        #pragma unroll
        for (int msk = 1; msk <= 8; msk <<= 1)
            contrib += __shfl_xor(contrib, msk);
        if (L15 == 0) sm[wv][quad * 4 + reg] = contrib;
    }
    __syncthreads();
    if (tid < 16) {
        const int tok = tok0 + tid;
        const int t = tok % Tn;
        if (t < Tn - 1) {
            const int sn = skill[tok + 1];
            const int ix = (sn < NUMC) ? sn : (NUMC - 1);
            const float val = sm[0][tid] + sm[1][tid] + pB[ix];
            out[(size_t)(tok / Tn) * (Tn - 1) + t] = (sn < NUMC) ? fast_sigmoid(val) : 0.f;
        }
    }
}

extern "C" void kernel_launch(void* const* d_in, const int* in_sizes, int n_in,
                              void* d_out, int out_size, void* d_ws, size_t ws_size,
                              hipStream_t stream)
{
    const int*   skill  = (const int*)  d_in[0];
    const int*   answer = (const int*)  d_in[1];
    const float* k_emb  = (const float*)d_in[2];
    const float* v_emb  = (const float*)d_in[3];
    const float* Mk     = (const float*)d_in[4];
    const float* Mv0    = (const float*)d_in[5];
    const float* f_W    = (const float*)d_in[6];
    const float* f_b    = (const float*)d_in[7];
    const float* p_W    = (const float*)d_in[8];
    const float* p_b    = (const float*)d_in[9];
    const float* e_W    = (const float*)d_in[10];
    const float* e_b    = (const float*)d_in[11];
    const float* a_W    = (const float*)d_in[12];
    const float* a_b    = (const float*)d_in[13];
    float* out = (float*)d_out;

    float* ws     = (float*)d_ws;
    float* w2     = ws;                                   // NTOK*64 (padded w layout)
    float* e_buf  = w2     + (size_t)NTOK*64;             // NTOK*DS
    float* a_buf  = e_buf  + (size_t)NTOK*DS;             // NTOK*DS
    float* kp_buf = a_buf  + (size_t)NTOK*DS;             // NTOK*DS
    unsigned short* reads = (unsigned short*)(kp_buf + (size_t)NTOK*DS);  // NTOK*DS bf16
    unsigned int* BeaU = (unsigned int*)(reads + (size_t)NTOK*DS);
    unsigned int* BkmU = BeaU + 4096 * 4;
    unsigned int* Bf0U = BkmU + 3072 * 4;

    k0_cast<<<36, 256, 0, stream>>>(e_W, a_W, f_W, Mk, BeaU, BkmU, Bf0U);
    k1_gemm<<<7*(NTOK/16), 64, 0, stream>>>(skill, answer, k_emb, v_emb,
        BeaU, BkmU, e_b, a_b, w2, e_buf, a_buf, kp_buf);
    k2_scan<<<Bsz*8, 64, 0, stream>>>(w2, e_buf, a_buf, Mv0, reads);
    k3_gemm<<<NTOK/16, 128, 0, stream>>>(reads, kp_buf, Bf0U, f_b,
        p_W, p_b, skill, out);
}

// Round 9
// 134.187 us; speedup vs baseline: 1.0543x; 1.0243x over previous
//
#include <hip/hip_runtime.h>
#include <math.h>

#define Bsz 64
#define Tn 200
#define NUMC 2000
#define DS 128
#define SM 50
#define NTOK (Bsz*Tn)

typedef __attribute__((ext_vector_type(8))) short bfrag;
typedef __attribute__((ext_vector_type(4))) float f32x4;
typedef __attribute__((ext_vector_type(4))) unsigned int u32x4;

__device__ __forceinline__ unsigned short f2bf(float x) {
    unsigned int u = __builtin_bit_cast(unsigned int, x);
    u = u + 0x7fffu + ((u >> 16) & 1u);   // RNE
    return (unsigned short)(u >> 16);
}
__device__ __forceinline__ unsigned int pack2(float a, float b) {
    return (unsigned int)f2bf(a) | ((unsigned int)f2bf(b) << 16);
}
__device__ __forceinline__ bfrag mk_frag(f32x4 x, f32x4 y) {
    u32x4 t;
    t[0] = pack2(x[0], x[1]); t[1] = pack2(x[2], x[3]);
    t[2] = pack2(y[0], y[1]); t[3] = pack2(y[2], y[3]);
    return __builtin_bit_cast(bfrag, t);
}

// fast transcendentals: v_exp_f32 / v_rcp_f32 (~1e-6 rel err, invisible at bf16 grade)
__device__ __forceinline__ float fast_exp(float x)  { return __builtin_amdgcn_exp2f(x * 1.44269504f); }
__device__ __forceinline__ float fast_rcp(float x)  { return __builtin_amdgcn_rcpf(x); }
__device__ __forceinline__ float fast_sigmoid(float x) { return fast_rcp(1.f + fast_exp(-x)); }
__device__ __forceinline__ float fast_tanh(float x) { return 1.f - 2.f * fast_rcp(fast_exp(2.f * x) + 1.f); }

// ---------------- K0: cast weights into MFMA b-frag block layout ----------------
// lane L holds W[n = nt*16 + (L&15)][k = ki*32 + (L>>4)*8 + j], j=0..7.
// Bea: rows 0-127 = e_W, 128-255 = a_W          (16 n-tiles)
// Bkm: rows 0-127 = f_W[:,128:256], 128-177 = Mk, 178-191 = 0   (12 n-tiles)
// Bf0: rows 0-127 = f_W[:,0:128]                (8 n-tiles)
__global__ __launch_bounds__(256) void k0_cast(
    const float* __restrict__ eW, const float* __restrict__ aW,
    const float* __restrict__ fW, const float* __restrict__ Mk,
    unsigned int* __restrict__ BeaU, unsigned int* __restrict__ BkmU,
    unsigned int* __restrict__ Bf0U)
{
    const int g = blockIdx.x * 256 + threadIdx.x;
    if (g >= 9216) return;
    int gm, mat;
    unsigned int* dst;
    if (g < 4096)      { mat = 0; gm = g;        dst = BeaU; }
    else if (g < 7168) { mat = 1; gm = g - 4096; dst = BkmU; }
    else               { mat = 2; gm = g - 7168; dst = Bf0U; }
    const int nt = gm >> 8, r = gm & 255, ki = r >> 6, L = r & 63;
    const int n = nt * 16 + (L & 15);
    const int k = ki * 32 + (L >> 4) * 8;

    const float* src = nullptr;
    if (mat == 0) {
        src = (n < 128) ? (eW + (size_t)n * DS + k) : (aW + (size_t)(n - 128) * DS + k);
    } else if (mat == 1) {
        if (n < 128)      src = fW + (size_t)n * (2 * DS) + DS + k;
        else if (n < 128 + SM) src = Mk + (size_t)(n - 128) * DS + k;
    } else {
        src = fW + (size_t)n * (2 * DS) + k;
    }
    float v[8];
    #pragma unroll
    for (int j = 0; j < 8; j++) v[j] = src ? src[j] : 0.f;
    u32x4 o;
    o[0] = pack2(v[0], v[1]); o[1] = pack2(v[2], v[3]);
    o[2] = pack2(v[4], v[5]); o[3] = pack2(v[6], v[7]);
    ((u32x4*)dst)[gm] = o;
}

// ---------------- K1: 7 single-purpose waves per 16-token tile (5600 blocks) ----------------
// role 0/1: e cols 0-63/64-127 (V @ Bea[0:8],  sigmoid)
// role 2/3: a cols 0-63/64-127 (V @ Bea[8:16], tanh)
// role 4/5: kp cols 0-63/64-127 (K @ Bkm[0:8])
// role 6  : w logits (K @ Bkm[8:12]) + wave-parallel softmax -> w2[t][64] NATURAL order
//           (cols 0..49 = softmax w, cols 50..63 = 0)
__global__ __launch_bounds__(64, 4) void k1_gemm(
    const int* __restrict__ skill, const int* __restrict__ answer,
    const float* __restrict__ k_emb, const float* __restrict__ v_emb,
    const unsigned int* __restrict__ BeaU, const unsigned int* __restrict__ BkmU,
    const float* __restrict__ eB, const float* __restrict__ aB,
    float* __restrict__ w2, float* __restrict__ e_buf,
    float* __restrict__ a_buf, float* __restrict__ kp_buf)
{
    const int bid = blockIdx.x;
    const int tile = bid / 7, role = bid % 7;
    const int L = threadIdx.x, L15 = L & 15, quad = L >> 4;
    const int tok0 = tile * 16;
    const int tokA = tok0 + L15;
    const int row0 = tok0 + quad * 4;

    const int s = skill[tokA];
    const float* ap;
    if (role < 4) {
        const int an = answer[tokA];
        const int ax = (an == 2) ? 1 : an;
        ap = v_emb + ((size_t)(s + NUMC * ax)) * DS + quad * 8;
    } else {
        ap = k_emb + (size_t)s * DS + quad * 8;
    }
    bfrag Af[4];
    #pragma unroll
    for (int ki = 0; ki < 4; ki++) {
        const f32x4* a4 = (const f32x4*)(ap + ki * 32);
        Af[ki] = mk_frag(a4[0], a4[1]);
    }

    const bfrag* Bp = (role < 4) ? (const bfrag*)BeaU : (const bfrag*)BkmU;
    const int g0 = (role < 4) ? role * 4 : (role - 4) * 4;

    f32x4 acc[4];
    #pragma unroll
    for (int t = 0; t < 4; t++) acc[t] = (f32x4){0.f,0.f,0.f,0.f};

    // B in two 2-tile halves to keep VGPRs under the (64,4) cap
    #pragma unroll
    for (int half = 0; half < 2; half++) {
        bfrag bh[2][4];
        #pragma unroll
        for (int tt = 0; tt < 2; tt++)
            #pragma unroll
            for (int ki = 0; ki < 4; ki++)
                bh[tt][ki] = Bp[(size_t)((g0 + half * 2 + tt) * 4 + ki) * 64 + L];
        #pragma unroll
        for (int ki = 0; ki < 4; ki++)
            #pragma unroll
            for (int tt = 0; tt < 2; tt++)
                acc[half * 2 + tt] = __builtin_amdgcn_mfma_f32_16x16x32_bf16(
                    Af[ki], bh[tt][ki], acc[half * 2 + tt], 0, 0, 0);
    }

    if (role == 6) {
        #pragma unroll
        for (int reg = 0; reg < 4; reg++) {
            float mx = -1e30f;
            #pragma unroll
            for (int t = 0; t < 4; t++) { const int c = t * 16 + L15; if (c < SM) mx = fmaxf(mx, acc[t][reg]); }
            #pragma unroll
            for (int msk = 1; msk <= 8; msk <<= 1) mx = fmaxf(mx, __shfl_xor(mx, msk));
            float ex[4]; float ssum = 0.f;
            #pragma unroll
            for (int t = 0; t < 4; t++) {
                const int c = t * 16 + L15;
                ex[t] = (c < SM) ? fast_exp(acc[t][reg] - mx) : 0.f;
                ssum += ex[t];
            }
            #pragma unroll
            for (int msk = 1; msk <= 8; msk <<= 1) ssum += __shfl_xor(ssum, msk);
            const float inv = fast_rcp(ssum);
            float* wp = w2 + (size_t)(row0 + reg) * 64;
            // natural order: col c = m for c<50; c>=50 gets ex=0 (zero pad)
            #pragma unroll
            for (int t = 0; t < 4; t++) {
                const int c = t * 16 + L15;
                wp[c] = ex[t] * inv;
            }
        }
    } else {
        const int nb = (role & 1) * 64;
        float* obuf = (role < 2) ? e_buf : (role < 4) ? a_buf : kp_buf;
        const float* bias = (role < 2) ? eB : aB;
        #pragma unroll
        for (int t = 0; t < 4; t++) {
            const int n = nb + t * 16 + L15;
            const float bv = (role < 4) ? bias[n] : 0.f;
            #pragma unroll
            for (int reg = 0; reg < 4; reg++) {
                float v = acc[t][reg] + bv;
                if (role < 2)      v = fast_sigmoid(v);
                else if (role < 4) v = fast_tanh(v);
                obuf[(size_t)(row0 + reg) * DS + n] = v;
            }
        }
    }
}

// ---------------- K2: barrier-free scan; 2048 one-wave blocks (8 waves/CU) ----------------
// r8 post-mortem: 512 waves = 2/CU = half the SIMDs idle, 1 wave/busy-SIMD -> every
// L2/L3 load latency fully exposed (VALUBusy 16%, 516 cyc/t vs ~90 issue). Fix TLP+ILP:
//  - 64 b x 32 d-segments = 2048 waves (2/SIMD on every SIMD)
//  - lane = (mg 0..15) x (dd 0..3): 16 m-groups x 4 m (m>=50: w==0 pads), 4 d/wave
//  - w2[t][64] natural order -> lane's 4 w = one fully-coalesced b128 (256 B/instr);
//    VMEM = 3 instrs/t (was 6)
//  - 4-slot x 4-t register ring (16-t lookahead, ~24 VGPR/slot -> no spill, ~130 total)
//  - m-reduce = 4x shfl_xor (masks 4,8,16,32), independent across the 4 buffered t
//  - store: lanes mg<4 emit (t0+mg, dd) via static cndmask select (no dynamic index)
__global__ __launch_bounds__(64) void k2_scan(
    const float* __restrict__ w2, const float* __restrict__ e_buf,
    const float* __restrict__ a_buf, const float* __restrict__ Mv0,
    unsigned short* __restrict__ reads)
{
    const int bid  = blockIdx.x;            // 0..2047
    const int b    = bid >> 5;
    const int dseg = bid & 31;
    const int lane = threadIdx.x;
    const int mg   = lane >> 2;             // 0..15 m-group
    const int dd   = lane & 3;
    const int d    = dseg * 4 + dd;
    const int m0   = mg * 4;
    const int base = b * Tn;

    float Mv[4];
    #pragma unroll
    for (int j = 0; j < 4; j++) {
        const int m = (m0 + j < SM) ? (m0 + j) : (SM - 1);  // pad slots: finite value, w=0 forever
        Mv[j] = Mv0[(size_t)m * DS + d];
    }

    // 4-slot x 4-t register ring
    float ev[4][4], av[4][4];
    f32x4 wv[4][4];

    #define LOADS(S, T0)                                                       \
        { _Pragma("unroll")                                                    \
          for (int i_ = 0; i_ < 4; i_++) {                                     \
              const int t_ = (T0) + i_;                                        \
              const int tc_ = (t_ < Tn) ? t_ : 0;                              \
              ev[S][i_] = e_buf[(size_t)(base + tc_) * DS + d];                \
              av[S][i_] = a_buf[(size_t)(base + tc_) * DS + d];                \
              wv[S][i_] = *(const f32x4*)(w2 + (size_t)(base + tc_) * 64 + m0);\
          } }

    #define PROC4(S, T0)                                                       \
        { float r4[4];                                                         \
          _Pragma("unroll")                                                    \
          for (int it = 0; it < 4; it++) {                                     \
              const float ev_ = ev[S][it], av_ = av[S][it];                    \
              float rd = 0.f;                                                  \
              _Pragma("unroll")                                                \
              for (int j = 0; j < 4; j++) {                                    \
                  const float wm = wv[S][it][j];                               \
                  rd = fmaf(wm, Mv[j], rd);                        /* old Mv */\
                  Mv[j] = fmaf(-wm, fmaf(ev_, Mv[j], -av_), Mv[j]);            \
              }                                                                \
              rd += __shfl_xor(rd, 4);                                         \
              rd += __shfl_xor(rd, 8);                                         \
              rd += __shfl_xor(rd, 16);                                        \
              rd += __shfl_xor(rd, 32);                                        \
              r4[it] = rd;                                                     \
          }                                                                    \
          if (mg < 4) {                                                        \
              const float val = (mg == 0) ? r4[0] : (mg == 1) ? r4[1]          \
                              : (mg == 2) ? r4[2] : r4[3];                     \
              reads[(size_t)(base + (T0) + mg) * DS + d] = f2bf(val);          \
          } }

    LOADS(0, 0) LOADS(1, 4) LOADS(2, 8) LOADS(3, 12)

    // 12 x 16t + 8t tail = 200
    for (int blk = 0; blk < 12; blk++) {
        const int t0 = blk * 16;
        PROC4(0, t0)      LOADS(0, t0 + 16)
        PROC4(1, t0 + 4)  LOADS(1, t0 + 20)
        PROC4(2, t0 + 8)  LOADS(2, t0 + 24)
        PROC4(3, t0 + 12) LOADS(3, t0 + 28)
    }
    PROC4(0, 192)
    PROC4(1, 196)
    #undef LOADS
    #undef PROC4
}

// ---------------- K3: 2-wave blocks (n-halves); f-GEMM + pred with LDS combine ----------------
__global__ __launch_bounds__(128, 2) void k3_gemm(
    const unsigned short* __restrict__ reads, const float* __restrict__ kp_buf,
    const unsigned int* __restrict__ Bf0U, const float* __restrict__ fB,
    const float* __restrict__ pW, const float* __restrict__ pB,
    const int* __restrict__ skill, float* __restrict__ out)
{
    const int tid = threadIdx.x;
    const int wv  = tid >> 6;          // n-half: 0 -> cols 0-63, 1 -> cols 64-127
    const int L   = tid & 63, L15 = L & 15, quad = L >> 4;
    const int tok0 = blockIdx.x * 16;
    const int tokA = tok0 + L15;
    const int row0 = tok0 + quad * 4;

    __shared__ float sm[2][16];

    // A-frags: final reads, already bf16 in frag element order
    bfrag Rf[4];
    #pragma unroll
    for (int ki = 0; ki < 4; ki++)
        Rf[ki] = *(const bfrag*)(reads + (size_t)tokA * DS + ki * 32 + quad * 8);

    const bfrag* Bf0 = (const bfrag*)Bf0U;
    const int g0 = wv * 4;

    f32x4 acc[4];
    #pragma unroll
    for (int t = 0; t < 4; t++) acc[t] = (f32x4){0.f,0.f,0.f,0.f};

    #pragma unroll
    for (int half = 0; half < 2; half++) {
        bfrag bh[2][4];
        #pragma unroll
        for (int tt = 0; tt < 2; tt++)
            #pragma unroll
            for (int ki = 0; ki < 4; ki++)
                bh[tt][ki] = Bf0[(size_t)((g0 + half * 2 + tt) * 4 + ki) * 64 + L];
        #pragma unroll
        for (int ki = 0; ki < 4; ki++)
            #pragma unroll
            for (int tt = 0; tt < 2; tt++)
                acc[half * 2 + tt] = __builtin_amdgcn_mfma_f32_16x16x32_bf16(
                    Rf[ki], bh[tt][ki], acc[half * 2 + tt], 0, 0, 0);
    }

    const int nb = wv * 64;
    float f[4][4];   // [reg][t]
    #pragma unroll
    for (int t = 0; t < 4; t++) {
        const int n = nb + t * 16 + L15;
        const float fb = fB[n];
        #pragma unroll
        for (int reg = 0; reg < 4; reg++)
            f[reg][t] = fast_tanh(acc[t][reg] + kp_buf[(size_t)(row0 + reg) * DS + n] + fb);
    }

    // pred partial: this wave's 64-dim contribution, reduced over the 16 lanes (L15)
    #pragma unroll
    for (int reg = 0; reg < 4; reg++) {
        const int tok = row0 + reg;
        const int t = tok % Tn;
        const bool act = (t < Tn - 1);
        float contrib = 0.f;
        if (act) {
            const int sn = skill[tok + 1];
            const int ix = (sn < NUMC) ? sn : (NUMC - 1);
            const float* pr = pW + (size_t)ix * DS + nb + L15;
            #pragma unroll
            for (int t4 = 0; t4 < 4; t4++)
                contrib = fmaf(f[reg][t4], pr[t4 * 16], contrib);
        }
        #pragma unroll
        for (int msk = 1; msk <= 8; msk <<= 1)
            contrib += __shfl_xor(contrib, msk);
        if (L15 == 0) sm[wv][quad * 4 + reg] = contrib;
    }
    __syncthreads();
    if (tid < 16) {
        const int tok = tok0 + tid;
        const int t = tok % Tn;
        if (t < Tn - 1) {
            const int sn = skill[tok + 1];
            const int ix = (sn < NUMC) ? sn : (NUMC - 1);
            const float val = sm[0][tid] + sm[1][tid] + pB[ix];
            out[(size_t)(tok / Tn) * (Tn - 1) + t] = (sn < NUMC) ? fast_sigmoid(val) : 0.f;
        }
    }
}

extern "C" void kernel_launch(void* const* d_in, const int* in_sizes, int n_in,
                              void* d_out, int out_size, void* d_ws, size_t ws_size,
                              hipStream_t stream)
{
    const int*   skill  = (const int*)  d_in[0];
    const int*   answer = (const int*)  d_in[1];
    const float* k_emb  = (const float*)d_in[2];
    const float* v_emb  = (const float*)d_in[3];
    const float* Mk     = (const float*)d_in[4];
    const float* Mv0    = (const float*)d_in[5];
    const float* f_W    = (const float*)d_in[6];
    const float* f_b    = (const float*)d_in[7];
    const float* p_W    = (const float*)d_in[8];
    const float* p_b    = (const float*)d_in[9];
    const float* e_W    = (const float*)d_in[10];
    const float* e_b    = (const float*)d_in[11];
    const float* a_W    = (const float*)d_in[12];
    const float* a_b    = (const float*)d_in[13];
    float* out = (float*)d_out;

    float* ws     = (float*)d_ws;
    float* w2     = ws;                                   // NTOK*64 (natural-order w + zero pad)
    float* e_buf  = w2     + (size_t)NTOK*64;             // NTOK*DS
    float* a_buf  = e_buf  + (size_t)NTOK*DS;             // NTOK*DS
    float* kp_buf = a_buf  + (size_t)NTOK*DS;             // NTOK*DS
    unsigned short* reads = (unsigned short*)(kp_buf + (size_t)NTOK*DS);  // NTOK*DS bf16
    unsigned int* BeaU = (unsigned int*)(reads + (size_t)NTOK*DS);
    unsigned int* BkmU = BeaU + 4096 * 4;
    unsigned int* Bf0U = BkmU + 3072 * 4;

    k0_cast<<<36, 256, 0, stream>>>(e_W, a_W, f_W, Mk, BeaU, BkmU, Bf0U);
    k1_gemm<<<7*(NTOK/16), 64, 0, stream>>>(skill, answer, k_emb, v_emb,
        BeaU, BkmU, e_b, a_b, w2, e_buf, a_buf, kp_buf);
    k2_scan<<<Bsz*32, 64, 0, stream>>>(w2, e_buf, a_buf, Mv0, reads);
    k3_gemm<<<NTOK/16, 128, 0, stream>>>(reads, kp_buf, Bf0U, f_b,
        p_W, p_b, skill, out);
}